// Round 16
// baseline (128.555 us; speedup 1.0000x reference)
//
#include <hip/hip_runtime.h>

// Problem constants (fixed by the reference)
#define BATCH   32
#define C_OUT_N 128
#define NK      5
#define C_IN_N  (NK * C_OUT_N)   // 640
#define HIN     58
#define WIN     58
#define HOUT    56
#define WOUT    56
#define NPIX    (HOUT * WOUT)                       // 3136
#define NTILE   (HOUT * (WOUT / 8))                 // 392 8-px tiles
#define OUT_PLANE ((size_t)BATCH * C_OUT_N * NPIX)  // 12,845,056

// Shift set fixed: REAL_PAD[t] = 4 - 3*t -> {4,1,-2,-5,-8}
// R16: channel-level double-buffered pipeline. LDS = TWO 1-channel buffers
// [58][70] f16 (cols 7-left-pad, data 7..64, 5 zeros right). Stage ch k+1
// (global->regs, issued BEFORE compute) while computing ch k from buf[k&1];
// regs->LDS write lands between barriers. HBM streaming overlaps DS/VALU.
// Compute body = R10 winner: b32 f16-pairs (stride 70 = odd dwords), pk-FMA,
// uniform weight-skip branches.
// LDS = 2*58*70*2 = 16,240 B; 512 thr -> 4 blocks/CU (thread-limited), 100% occ.
#define NTHREADS   512
#define LDS_STRIDE 70                        // f16 elements
#define CH_HALVES  (HIN * LDS_STRIDE)        // 4060 per buffer
#define LDS_HALVES (2 * CH_HALVES)           // 8120 -> 16,240 B
#define NV4C       (HIN * WIN / 4)           // 841 float4s per channel

typedef _Float16 h2 __attribute__((ext_vector_type(2)));

static __device__ __forceinline__ unsigned int h2u(h2 v) {
    unsigned int r; __builtin_memcpy(&r, &v, 4); return r;
}
static __device__ __forceinline__ h2 uh2(unsigned int u) {
    h2 r; __builtin_memcpy(&r, &u, 4); return r;
}
// shifted-by-one-column f16 pair via v_alignbit_b32
static __device__ __forceinline__ h2 algn(h2 lo, h2 hi) {
    return uh2(__builtin_amdgcn_alignbit(h2u(hi), h2u(lo), 16));
}
// packed f32x2 -> f16x2 (round-toward-zero), bit-cast to our h2 type
static __device__ __forceinline__ h2 pkrtz(float a, float b) {
    auto t = __builtin_amdgcn_cvt_pkrtz(a, b);   // __fp16 ext_vector(2)
    h2 r; __builtin_memcpy(&r, &t, 4); return r;
}
static __device__ __forceinline__ float uni(float v) {   // force SGPR (block-uniform)
    return __uint_as_float(__builtin_amdgcn_readfirstlane(__float_as_uint(v)));
}

__global__ __launch_bounds__(NTHREADS, 8) void addshift_pipe_kernel(
    const float* __restrict__ x,          // (B, C_IN, 58, 58)
    const int*   __restrict__ pad_hv,     // (C_IN, 8): [0..3]=h shifts, [4..7]=v shifts
    const int*   __restrict__ idx_id,     // (C_OUT, 4), values in [co*5, co*5+5)
    float*       __restrict__ out)        // out_h | out_v | out_id concatenated
{
    extern __shared__ _Float16 lds[];

    const int bc  = blockIdx.x;           // b * C_OUT + co
    const int b   = bc / C_OUT_N;
    const int co  = bc - b * C_OUT_N;
    const int tid = threadIdx.x;

    const float* xbase = x + (size_t)(b * C_IN_N + co * NK) * (HIN * WIN);

    // ---- staging helpers (channel-local row/col; base r*70+7+c is odd, c even)
    auto issue_ch = [&](int k, float4& v1, float4& v2) {
        const float* src = xbase + k * (HIN * WIN);
        v1 = *(const float4*)(src + 4 * tid);
        if (tid < NV4C - NTHREADS)                    // 329 threads load a 2nd
            v2 = *(const float4*)(src + 4 * (tid + NTHREADS));
    };
    auto write_one = [&](int bsel, float4 v, int i4) {
        int g = 4 * i4;
        int r = g / 58;                               // 0..57
        int c = g - 58 * r;                           // even, 0..56
        _Float16* dst = &lds[bsel * CH_HALVES + r * LDS_STRIDE + 7 + c];
        if (c <= 54) {
            dst[0] = (_Float16)v.x;
            *(h2*)(dst + 1) = pkrtz(v.y, v.z);        // even idx, b32 write
            dst[3] = (_Float16)v.w;
        } else {                                      // c==56: wrap to next row
            dst[0] = (_Float16)v.x;
            dst[1] = (_Float16)v.y;
            _Float16* d2 = &lds[bsel * CH_HALVES + (r + 1) * LDS_STRIDE + 7];
            d2[0] = (_Float16)v.z;
            d2[1] = (_Float16)v.w;
        }
    };
    auto write_ch = [&](int bsel, float4 v1, float4 v2) {
        write_one(bsel, v1, tid);
        if (tid < NV4C - NTHREADS) write_one(bsel, v2, tid + NTHREADS);
    };

    // ---- zero column margins of BOTH buffers (cols 0..6 and 65..69)
    for (int i = tid; i < 2 * HIN * 12; i += NTHREADS) {
        int bsel = i / (HIN * 12);
        int m2   = i - bsel * (HIN * 12);
        int row  = m2 / 12;
        int m    = m2 - row * 12;
        int c    = (m < 7) ? m : (58 + m);
        lds[bsel * CH_HALVES + row * LDS_STRIDE + c] = (_Float16)0.f;
    }

    // ---- prologue: issue ch0 loads; weight build covers their latency
    float4 s1, s2;
    issue_ch(0, s1, s2);

    // block-uniform shift multiplicities -> SGPR floats (R10 verbatim)
    float mhf[NK][5], mvf[NK][5], cntf[NK];
    #pragma unroll
    for (int k = 0; k < NK; ++k) {
        #pragma unroll
        for (int t = 0; t < 5; ++t) { mhf[k][t] = 0.f; mvf[k][t] = 0.f; }
        cntf[k] = 0.f;
        #pragma unroll
        for (int g = 0; g < 4; ++g) {
            int sh_v = pad_hv[(co * NK + k) * 8 + g];       // in {4,1,-2,-5,-8}
            int th   = (4 - sh_v) / 3;                      // slot 0..4
            int sv_v = pad_hv[(co * NK + k) * 8 + 4 + g];
            int tv   = (4 - sv_v) / 3;
            #pragma unroll
            for (int t = 0; t < 5; ++t) {
                mhf[k][t] += (th == t) ? 1.f : 0.f;
                mvf[k][t] += (tv == t) ? 1.f : 0.f;
            }
        }
    }
    #pragma unroll
    for (int g = 0; g < 4; ++g) {
        int c = idx_id[co * 4 + g] - co * NK;               // 0..4
        #pragma unroll
        for (int k = 0; k < NK; ++k) cntf[k] += (c == k) ? 1.f : 0.f;
    }
    #pragma unroll
    for (int k = 0; k < NK; ++k) {
        cntf[k] = uni(cntf[k]);
        #pragma unroll
        for (int t = 0; t < 5; ++t) { mhf[k][t] = uni(mhf[k][t]); mvf[k][t] = uni(mvf[k][t]); }
    }

    write_ch(0, s1, s2);                  // ch0 -> buf0 (waits vmcnt internally)
    issue_ch(1, s1, s2);                  // ch1 loads in flight across barrier
    __syncthreads();                      // buf0 + margins visible

    // ---- per-tile constants
    const int q  = tid;
    const int h  = q / 7;
    const int w0 = 8 * (q - h * 7);
    int  voff[5];
    bool okv[5];
    #pragma unroll
    for (int t = 0; t < 5; ++t) {
        int rr = h + 5 - 3 * t;           // h+1+(4-3t)
        okv[t] = (unsigned)rr < 58u;
        int rc = rr < 0 ? 0 : (rr > 57 ? 57 : rr);
        voff[t] = rc * LDS_STRIDE + w0 + 8;
    }
    const int rowbase = (h + 1) * LDS_STRIDE + w0;

    h2 sh[4], sv[4], si[4];
    #pragma unroll
    for (int m = 0; m < 4; ++m) {
        sh[m] = h2{(_Float16)0.f, (_Float16)0.f};
        sv[m] = sh[m]; si[m] = sh[m];
    }

    // ---- pipelined main loop: compute ch k while ch k+1 streams from HBM
    #pragma unroll
    for (int k = 0; k < NK; ++k) {
        const int cb = (k & 1) * CH_HALVES;

        if (q < NTILE) {
            const _Float16* chp  = lds + cb;
            const _Float16* rowp = chp + rowbase;

            // 20-col window as 10 f16-pairs (b32 loads, 4B-aligned)
            h2 H[10];
            #pragma unroll
            for (int m = 0; m < 10; ++m) H[m] = *(const h2*)(rowp + 2 * m);

            // out_h: tap t -> j = 12-3t; uniform skip of zero-weight taps
            #pragma unroll
            for (int t = 0; t < 5; ++t) {
                float wg = mhf[k][t];
                if (wg != 0.f) {
                    _Float16 wh = (_Float16)wg;
                    h2 w2 = h2{wh, wh};
                    int j = 12 - 3 * t;
                    if ((j & 1) == 0) {
                        int m0 = j >> 1;
                        #pragma unroll
                        for (int m = 0; m < 4; ++m) sh[m] += w2 * H[m0 + m];
                    } else {
                        int m0 = (j - 1) >> 1;
                        #pragma unroll
                        for (int m = 0; m < 4; ++m)
                            sh[m] += w2 * algn(H[m0 + m], H[m0 + m + 1]);
                    }
                }
            }

            // out_id: center cols 8..15 = H[4..7]
            float ck = cntf[k];
            if (ck != 0.f) {
                _Float16 c16 = (_Float16)ck;
                h2 c2 = h2{c16, c16};
                #pragma unroll
                for (int m = 0; m < 4; ++m) si[m] += c2 * H[4 + m];
            }

            // out_v: 4 pair-loads per nonzero tap; OOB -> weight zeroed
            #pragma unroll
            for (int t = 0; t < 5; ++t) {
                float wv = mvf[k][t];
                if (wv != 0.f) {
                    float wm = okv[t] ? wv : 0.f;
                    _Float16 wh = (_Float16)wm;
                    h2 w2 = h2{wh, wh};
                    const _Float16* vp = chp + voff[t];
                    #pragma unroll
                    for (int m = 0; m < 4; ++m)
                        sv[m] += w2 * *(const h2*)(vp + 2 * m);
                }
            }
        }

        if (k < NK - 1) {
            __syncthreads();              // all done reading buf[(k+1)&1] (ch k-1)
            write_ch((k + 1) & 1, s1, s2);        // vmcnt wait hidden by compute
            if (k < NK - 2) issue_ch(k + 2, s1, s2);
            __syncthreads();              // buf[(k+1)&1] now holds ch k+1
        }
    }

    // ---- store
    if (q < NTILE) {
        size_t o = (size_t)bc * NPIX + h * WOUT + w0;
        *(float4*)(out + o) =
            make_float4((float)sh[0].x, (float)sh[0].y, (float)sh[1].x, (float)sh[1].y);
        *(float4*)(out + o + 4) =
            make_float4((float)sh[2].x, (float)sh[2].y, (float)sh[3].x, (float)sh[3].y);
        *(float4*)(out + OUT_PLANE + o) =
            make_float4((float)sv[0].x, (float)sv[0].y, (float)sv[1].x, (float)sv[1].y);
        *(float4*)(out + OUT_PLANE + o + 4) =
            make_float4((float)sv[2].x, (float)sv[2].y, (float)sv[3].x, (float)sv[3].y);
        *(float4*)(out + 2 * OUT_PLANE + o) =
            make_float4((float)si[0].x, (float)si[0].y, (float)si[1].x, (float)si[1].y);
        *(float4*)(out + 2 * OUT_PLANE + o + 4) =
            make_float4((float)si[2].x, (float)si[2].y, (float)si[3].x, (float)si[3].y);
    }
}

extern "C" void kernel_launch(void* const* d_in, const int* in_sizes, int n_in,
                              void* d_out, int out_size, void* d_ws, size_t ws_size,
                              hipStream_t stream) {
    const float* x      = (const float*)d_in[0];
    const int*   pad_hv = (const int*)d_in[1];
    const int*   idx_id = (const int*)d_in[2];
    float*       out    = (float*)d_out;

    addshift_pipe_kernel<<<dim3(BATCH * C_OUT_N), dim3(NTHREADS),
                           LDS_HALVES * 2, stream>>>(x, pad_hv, idx_id, out);
}

// Round 17
// 115.242 us; speedup vs baseline: 1.1155x; 1.1155x over previous
//
#include <hip/hip_runtime.h>

// Problem constants (fixed by the reference)
#define BATCH   32
#define C_OUT_N 128
#define NK      5
#define C_IN_N  (NK * C_OUT_N)   // 640
#define HIN     58
#define WIN     58
#define HOUT    56
#define WOUT    56
#define NPIX    (HOUT * WOUT)                       // 3136
#define NTILE   (HOUT * (WOUT / 8))                 // 392 8-px tiles
#define HTILE   (NTILE / 2)                         // 196 per half
#define OUT_PLANE ((size_t)BATCH * C_OUT_N * NPIX)  // 12,845,056

// Shift set fixed: REAL_PAD[t] = 4 - 3*t -> {4,1,-2,-5,-8}
// R17: R10 structure (stride-70 f16 LDS, b32-pair loads, pk-FMA, uniform
// weight-skip branches) but 256 threads x TWO tiles per thread with
// k-interleaved bodies -> 2 independent dependency chains per wave
// (intra-wave ILP covers DS latency instead of cross-wave slack).
// LDS = 290*70*2 = 40,600 B -> 4 blocks/CU; 16 waves/CU.
#define NTHREADS   256
#define LDS_STRIDE 70                        // f16 elements
#define LDS_ROWS   (NK * HIN)                // 290
#define LDS_HALVES (LDS_ROWS * LDS_STRIDE)   // 20,300 -> 40,600 B
#define CH_STRIDE  (HIN * LDS_STRIDE)        // 4060
#define NV4        (NK * HIN * WIN / 4)      // 4205 float4s per (b,co) chunk

typedef _Float16 h2 __attribute__((ext_vector_type(2)));

static __device__ __forceinline__ unsigned int h2u(h2 v) {
    unsigned int r; __builtin_memcpy(&r, &v, 4); return r;
}
static __device__ __forceinline__ h2 uh2(unsigned int u) {
    h2 r; __builtin_memcpy(&r, &u, 4); return r;
}
// shifted-by-one-column f16 pair via v_alignbit_b32
static __device__ __forceinline__ h2 algn(h2 lo, h2 hi) {
    return uh2(__builtin_amdgcn_alignbit(h2u(hi), h2u(lo), 16));
}
// packed f32x2 -> f16x2 (round-toward-zero), bit-cast to our h2 type
static __device__ __forceinline__ h2 pkrtz(float a, float b) {
    auto t = __builtin_amdgcn_cvt_pkrtz(a, b);   // __fp16 ext_vector(2)
    h2 r; __builtin_memcpy(&r, &t, 4); return r;
}
static __device__ __forceinline__ float uni(float v) {   // force SGPR (block-uniform)
    return __uint_as_float(__builtin_amdgcn_readfirstlane(__float_as_uint(v)));
}

__global__ __launch_bounds__(NTHREADS, 4) void addshift_ilp2_kernel(
    const float* __restrict__ x,          // (B, C_IN, 58, 58)
    const int*   __restrict__ pad_hv,     // (C_IN, 8): [0..3]=h shifts, [4..7]=v shifts
    const int*   __restrict__ idx_id,     // (C_OUT, 4), values in [co*5, co*5+5)
    float*       __restrict__ out)        // out_h | out_v | out_id concatenated
{
    extern __shared__ _Float16 lds[];

    const int bc  = blockIdx.x;           // b * C_OUT + co
    const int b   = bc / C_OUT_N;
    const int co  = bc - b * C_OUT_N;
    const int tid = threadIdx.x;

    // ---- zero the column margins (12 per row: 0..6 and 65..69)
    for (int i = tid; i < LDS_ROWS * 12; i += NTHREADS) {
        int j = i / 12;
        int m = i - j * 12;
        int c = (m < 7) ? m : (58 + m);
        lds[j * LDS_STRIDE + c] = (_Float16)0.f;
    }

    // ---- stage 5-channel chunk: float4 global loads -> f16 LDS
    const float* xbase = x + (size_t)(b * C_IN_N + co * NK) * (HIN * WIN);
    for (int i = tid; i < NV4; i += NTHREADS) {
        int g = 4 * i;
        float4 v = *(const float4*)(xbase + g);
        int r = g / 58;                   // const division -> magic mul
        int c = g - r * 58;               // even, 0..56
        _Float16* dst = &lds[r * LDS_STRIDE + 7 + c];
        if (c <= 54) {
            dst[0] = (_Float16)v.x;
            *(h2*)(dst + 1) = pkrtz(v.y, v.z);   // even idx, b32 write
            dst[3] = (_Float16)v.w;
        } else {                          // c == 56: last 2 floats wrap to next row
            dst[0] = (_Float16)v.x;
            dst[1] = (_Float16)v.y;
            _Float16* d2 = &lds[(r + 1) * LDS_STRIDE + 7];
            d2[0] = (_Float16)v.z;
            d2[1] = (_Float16)v.w;
        }
    }

    // ---- block-uniform shift multiplicities -> SGPR floats (R10 verbatim)
    float mhf[NK][5], mvf[NK][5], cntf[NK];
    #pragma unroll
    for (int k = 0; k < NK; ++k) {
        #pragma unroll
        for (int t = 0; t < 5; ++t) { mhf[k][t] = 0.f; mvf[k][t] = 0.f; }
        cntf[k] = 0.f;
        #pragma unroll
        for (int g = 0; g < 4; ++g) {
            int sh_v = pad_hv[(co * NK + k) * 8 + g];       // in {4,1,-2,-5,-8}
            int th   = (4 - sh_v) / 3;                      // slot 0..4
            int sv_v = pad_hv[(co * NK + k) * 8 + 4 + g];
            int tv   = (4 - sv_v) / 3;
            #pragma unroll
            for (int t = 0; t < 5; ++t) {
                mhf[k][t] += (th == t) ? 1.f : 0.f;
                mvf[k][t] += (tv == t) ? 1.f : 0.f;
            }
        }
    }
    #pragma unroll
    for (int g = 0; g < 4; ++g) {
        int c = idx_id[co * 4 + g] - co * NK;               // 0..4
        #pragma unroll
        for (int k = 0; k < NK; ++k) cntf[k] += (c == k) ? 1.f : 0.f;
    }
    #pragma unroll
    for (int k = 0; k < NK; ++k) {
        cntf[k] = uni(cntf[k]);
        #pragma unroll
        for (int t = 0; t < 5; ++t) { mhf[k][t] = uni(mhf[k][t]); mvf[k][t] = uni(mvf[k][t]); }
    }

    __syncthreads();

    // ---- compute: TWO tiles per thread (tid and tid+196), k-interleaved
    if (tid < HTILE) {
        const int qa  = tid;
        const int ha  = qa / 7;
        const int w0a = 8 * (qa - ha * 7);
        const int qb  = qa + HTILE;
        const int hb  = qb / 7;
        const int w0b = 8 * (qb - hb * 7);

        int  voffa[5], voffb[5];
        bool okva[5],  okvb[5];
        #pragma unroll
        for (int t = 0; t < 5; ++t) {
            int ra = ha + 5 - 3 * t;
            okva[t] = (unsigned)ra < 58u;
            int rca = ra < 0 ? 0 : (ra > 57 ? 57 : ra);
            voffa[t] = rca * LDS_STRIDE + w0a + 8;
            int rb = hb + 5 - 3 * t;
            okvb[t] = (unsigned)rb < 58u;
            int rcb = rb < 0 ? 0 : (rb > 57 ? 57 : rb);
            voffb[t] = rcb * LDS_STRIDE + w0b + 8;
        }
        const int rowba = (ha + 1) * LDS_STRIDE + w0a;
        const int rowbb = (hb + 1) * LDS_STRIDE + w0b;

        h2 sha[4], sva[4], sia[4], shb[4], svb[4], sib[4];
        #pragma unroll
        for (int m = 0; m < 4; ++m) {
            sha[m] = h2{(_Float16)0.f, (_Float16)0.f};
            sva[m] = sha[m]; sia[m] = sha[m];
            shb[m] = sha[m]; svb[m] = sha[m]; sib[m] = sha[m];
        }

        #pragma unroll
        for (int k = 0; k < NK; ++k) {
            const _Float16* chp   = lds + k * CH_STRIDE;
            const _Float16* rowpa = chp + rowba;
            const _Float16* rowpb = chp + rowbb;

            // two independent 10-pair windows: 20 b32 loads back-to-back
            h2 Ha[10], Hb[10];
            #pragma unroll
            for (int m = 0; m < 10; ++m) Ha[m] = *(const h2*)(rowpa + 2 * m);
            #pragma unroll
            for (int m = 0; m < 10; ++m) Hb[m] = *(const h2*)(rowpb + 2 * m);

            // out_h: tap t -> j = 12-3t; uniform skip; both chains per tap
            #pragma unroll
            for (int t = 0; t < 5; ++t) {
                float wg = mhf[k][t];
                if (wg != 0.f) {
                    _Float16 wh = (_Float16)wg;
                    h2 w2 = h2{wh, wh};
                    int j = 12 - 3 * t;
                    if ((j & 1) == 0) {
                        int m0 = j >> 1;
                        #pragma unroll
                        for (int m = 0; m < 4; ++m) {
                            sha[m] += w2 * Ha[m0 + m];
                            shb[m] += w2 * Hb[m0 + m];
                        }
                    } else {
                        int m0 = (j - 1) >> 1;
                        #pragma unroll
                        for (int m = 0; m < 4; ++m) {
                            sha[m] += w2 * algn(Ha[m0 + m], Ha[m0 + m + 1]);
                            shb[m] += w2 * algn(Hb[m0 + m], Hb[m0 + m + 1]);
                        }
                    }
                }
            }

            // out_id: center cols 8..15 = H[4..7]
            float ck = cntf[k];
            if (ck != 0.f) {
                _Float16 c16 = (_Float16)ck;
                h2 c2 = h2{c16, c16};
                #pragma unroll
                for (int m = 0; m < 4; ++m) {
                    sia[m] += c2 * Ha[4 + m];
                    sib[m] += c2 * Hb[4 + m];
                }
            }

            // out_v: per nonzero tap, both chains' loads then both FMA sets
            #pragma unroll
            for (int t = 0; t < 5; ++t) {
                float wv = mvf[k][t];
                if (wv != 0.f) {
                    const _Float16* vpa = chp + voffa[t];
                    const _Float16* vpb = chp + voffb[t];
                    h2 Va[4], Vb[4];
                    #pragma unroll
                    for (int m = 0; m < 4; ++m) Va[m] = *(const h2*)(vpa + 2 * m);
                    #pragma unroll
                    for (int m = 0; m < 4; ++m) Vb[m] = *(const h2*)(vpb + 2 * m);
                    float wma = okva[t] ? wv : 0.f;
                    float wmb = okvb[t] ? wv : 0.f;
                    _Float16 wa16 = (_Float16)wma;
                    _Float16 wb16 = (_Float16)wmb;
                    h2 wa2 = h2{wa16, wa16};
                    h2 wb2 = h2{wb16, wb16};
                    #pragma unroll
                    for (int m = 0; m < 4; ++m) {
                        sva[m] += wa2 * Va[m];
                        svb[m] += wb2 * Vb[m];
                    }
                }
            }
        }

        // ---- stores for both tiles
        size_t oa = (size_t)bc * NPIX + ha * WOUT + w0a;
        size_t ob = (size_t)bc * NPIX + hb * WOUT + w0b;
        *(float4*)(out + oa) =
            make_float4((float)sha[0].x, (float)sha[0].y, (float)sha[1].x, (float)sha[1].y);
        *(float4*)(out + oa + 4) =
            make_float4((float)sha[2].x, (float)sha[2].y, (float)sha[3].x, (float)sha[3].y);
        *(float4*)(out + ob) =
            make_float4((float)shb[0].x, (float)shb[0].y, (float)shb[1].x, (float)shb[1].y);
        *(float4*)(out + ob + 4) =
            make_float4((float)shb[2].x, (float)shb[2].y, (float)shb[3].x, (float)shb[3].y);
        *(float4*)(out + OUT_PLANE + oa) =
            make_float4((float)sva[0].x, (float)sva[0].y, (float)sva[1].x, (float)sva[1].y);
        *(float4*)(out + OUT_PLANE + oa + 4) =
            make_float4((float)sva[2].x, (float)sva[2].y, (float)sva[3].x, (float)sva[3].y);
        *(float4*)(out + OUT_PLANE + ob) =
            make_float4((float)svb[0].x, (float)svb[0].y, (float)svb[1].x, (float)svb[1].y);
        *(float4*)(out + OUT_PLANE + ob + 4) =
            make_float4((float)svb[2].x, (float)svb[2].y, (float)svb[3].x, (float)svb[3].y);
        *(float4*)(out + 2 * OUT_PLANE + oa) =
            make_float4((float)sia[0].x, (float)sia[0].y, (float)sia[1].x, (float)sia[1].y);
        *(float4*)(out + 2 * OUT_PLANE + oa + 4) =
            make_float4((float)sia[2].x, (float)sia[2].y, (float)sia[3].x, (float)sia[3].y);
        *(float4*)(out + 2 * OUT_PLANE + ob) =
            make_float4((float)sib[0].x, (float)sib[0].y, (float)sib[1].x, (float)sib[1].y);
        *(float4*)(out + 2 * OUT_PLANE + ob + 4) =
            make_float4((float)sib[2].x, (float)sib[2].y, (float)sib[3].x, (float)sib[3].y);
    }
}

extern "C" void kernel_launch(void* const* d_in, const int* in_sizes, int n_in,
                              void* d_out, int out_size, void* d_ws, size_t ws_size,
                              hipStream_t stream) {
    const float* x      = (const float*)d_in[0];
    const int*   pad_hv = (const int*)d_in[1];
    const int*   idx_id = (const int*)d_in[2];
    float*       out    = (float*)d_out;

    addshift_ilp2_kernel<<<dim3(BATCH * C_OUT_N), dim3(NTHREADS),
                           LDS_HALVES * 2, stream>>>(x, pad_hv, idx_id, out);
}